// Round 1
// baseline (116.072 us; speedup 1.0000x reference)
//
#include <hip/hip_runtime.h>

// Problem constants (from reference)
constexpr int B = 16384;
constexpr int S = 4;
constexpr int L = 16;
constexpr int D = 256;           // 256 floats per row = 64 lanes x float4
constexpr int BOS_ID = 98;

// Native vector type for nontemporal stores (HIP's float4 class is rejected
// by __builtin_nontemporal_store).
typedef float vfloat4 __attribute__((ext_vector_type(4)));

// One wave (64 lanes) = TWO batch elements = 10 output rows (10 KB stores).
//
// v2: the char-gather loop no longer guards each load with `if (l < len)`.
// Those guards put every global_load in its own basic block -> the compiler
// emitted {s_cbranch, load, s_waitcnt vmcnt(0), v_add} per character: a
// serial chain of ~200-cycle L2 hits (latency-bound, ~23% of HBM BW).
// Now: batch-issue 8 loads unconditionally (len >= 1 always), issue the
// next 8 behind a single wave-uniform `len > 8` branch (condition is SGPR
// data, no vmcnt wait), then accumulate with a {0,1} mask via fmac.
// fma(1,e,r) == e+r and fma(0,e,r) == r in f32, so the result is
// bit-identical to the guarded sequential sum.
__device__ __forceinline__ void process_elem(
    int b, int lane, int4 st4, int4 cl4, int4 ai4, int my_ids,
    const float* __restrict__ char_table,
    const float* __restrict__ action_table,
    vfloat4 bos, float* __restrict__ out)
{
    vfloat4* outv = reinterpret_cast<vfloat4*>(out + (size_t)b * 5 * D) + lane;
    __builtin_nontemporal_store(bos, &outv[0]);    // BOS row

    #pragma unroll
    for (int s = 0; s < S; ++s) {
        const int t   = (s == 0) ? st4.x : (s == 1) ? st4.y : (s == 2) ? st4.z : st4.w;
        const int len = (s == 0) ? cl4.x : (s == 1) ? cl4.y : (s == 2) ? cl4.z : cl4.w;
        const int aid = (s == 0) ? ai4.x : (s == 1) ? ai4.y : (s == 2) ? ai4.z : ai4.w;

        vfloat4 r = {0.f, 0.f, 0.f, 0.f};

        if (t == 1) {
            r = *(reinterpret_cast<const vfloat4*>(action_table + aid * D) + lane);
        } else if (t == 0) {
            vfloat4 e[L];   // gather staging; only e[0..7] live when len <= 8

            // First 8 gathers: always needed work for len in [1,8], and
            // issued back-to-back with no intervening waits.
            #pragma unroll
            for (int l = 0; l < 8; ++l) {
                const int id = __shfl(my_ids, s * L + l);   // v_readlane -> SGPR base
                e[l] = *(reinterpret_cast<const vfloat4*>(char_table + id * D) + lane);
            }

            if (len > 8) {          // wave-uniform; ~56% of slots skip these loads
                #pragma unroll
                for (int l = 8; l < L; ++l) {
                    const int id = __shfl(my_ids, s * L + l);
                    e[l] = *(reinterpret_cast<const vfloat4*>(char_table + id * D) + lane);
                }
                #pragma unroll
                for (int l = 0; l < L; ++l) {
                    const float m = (l < len) ? 1.0f : 0.0f;   // uniform -> s_cselect
                    r += m * e[l];                              // v_fmac, bit-exact mask
                }
            } else {
                #pragma unroll
                for (int l = 0; l < 8; ++l) {
                    const float m = (l < len) ? 1.0f : 0.0f;
                    r += m * e[l];
                }
            }

            const float flen = (float)len;
            r /= flen;                                 // exact f32 div, matches ref
        }
        // t == 2: zeros

        __builtin_nontemporal_store(r, &outv[(s + 1) * (D / 4)]);
    }
}

__global__ __launch_bounds__(256) void actions_emb_wave10(
    const int*   __restrict__ char_ids,     // (B,S,L) = (B,64)
    const int*   __restrict__ char_len,     // (B,S)
    const int*   __restrict__ action_ids,   // (B,S)
    const int*   __restrict__ slot_type,    // (B,S)
    const float* __restrict__ char_table,   // (58,D)
    const float* __restrict__ action_table, // (99,D)
    float*       __restrict__ out)          // (B,S+1,D)
{
    const int lane = threadIdx.x & 63;
    const int e    = (blockIdx.x * blockDim.x + threadIdx.x) >> 6;   // [0, B/2)
    const int b0   = e * 2, b1 = b0 + 1;

    // ---- all control loads for BOTH elements, issued together ----
    const int4 st0 = *reinterpret_cast<const int4*>(slot_type  + b0 * S);
    const int4 cl0 = *reinterpret_cast<const int4*>(char_len   + b0 * S);
    const int4 ai0 = *reinterpret_cast<const int4*>(action_ids + b0 * S);
    const int4 st1 = *reinterpret_cast<const int4*>(slot_type  + b1 * S);
    const int4 cl1 = *reinterpret_cast<const int4*>(char_len   + b1 * S);
    const int4 ai1 = *reinterpret_cast<const int4*>(action_ids + b1 * S);
    const int  ids0 = char_ids[b0 * (S * L) + lane];
    const int  ids1 = char_ids[b1 * (S * L) + lane];
    const vfloat4 bos = *(reinterpret_cast<const vfloat4*>(action_table + BOS_ID * D) + lane);

    process_elem(b0, lane, st0, cl0, ai0, ids0, char_table, action_table, bos, out);
    process_elem(b1, lane, st1, cl1, ai1, ids1, char_table, action_table, bos, out);
}

extern "C" void kernel_launch(void* const* d_in, const int* in_sizes, int n_in,
                              void* d_out, int out_size, void* d_ws, size_t ws_size,
                              hipStream_t stream) {
    const int*   char_ids     = (const int*)  d_in[0];
    const int*   char_len     = (const int*)  d_in[1];
    const int*   action_ids   = (const int*)  d_in[2];
    const int*   slot_type    = (const int*)  d_in[3];
    const float* char_table   = (const float*)d_in[4];
    const float* action_table = (const float*)d_in[5];
    float*       out          = (float*)      d_out;

    // One wave per 2 batch elements: B/2 = 8192 waves; 256-thread blocks -> 2048 blocks.
    const int blocks = B / 8;
    actions_emb_wave10<<<blocks, 256, 0, stream>>>(
        char_ids, char_len, action_ids, slot_type, char_table, action_table, out);
}

// Round 2
// 111.742 us; speedup vs baseline: 1.0387x; 1.0387x over previous
//
#include <hip/hip_runtime.h>

// Problem constants (from reference)
constexpr int B = 16384;
constexpr int S = 4;
constexpr int L = 16;
constexpr int D = 256;           // 256 floats per row = 64 lanes x float4
constexpr int BOS_ID = 98;

typedef float vfloat4 __attribute__((ext_vector_type(4)));

// v3: occupancy-first restructure.
//  - ONE batch element per wave (v2 had two): halves live register state,
//    doubles wave count (16384 waves = 64 waves/CU queued).
//  - All control data is wave-uniform; force it into SGPRs:
//    b via readfirstlane -> slot_type/char_len/action_ids/char_ids loads are
//    uniform (s_load), gather bases are SGPRs, stores use SGPR saddr.
//    This was the point of v2's __shfl, but now NO per-lane copy exists at all.
//  - Gathers in groups of 4 with compile-time indices (ids stay in SGPRs),
//    masked-fma accumulation in ascending l order: fma(1,e,r)==r+e,
//    fma(0,e,r)==r in f32, so the sum is bit-identical to the guarded
//    sequential sum that already passed (absmax unchanged).
//  - __launch_bounds__(256, 8) caps VGPRs at 64 -> 8 waves/SIMD.
__global__ __launch_bounds__(256, 8) void actions_emb_wave5(
    const int*   __restrict__ char_ids,     // (B,S,L) = (B,64)
    const int*   __restrict__ char_len,     // (B,S)
    const int*   __restrict__ action_ids,   // (B,S)
    const int*   __restrict__ slot_type,    // (B,S)
    const float* __restrict__ char_table,   // (58,D)
    const float* __restrict__ action_table, // (99,D)
    float*       __restrict__ out)          // (B,S+1,D)
{
    const int lane = threadIdx.x & 63;
    // one wave per batch element; readfirstlane makes b provably uniform
    const int b = __builtin_amdgcn_readfirstlane(
        (int)((blockIdx.x * blockDim.x + threadIdx.x) >> 6));

    // Wave-uniform control loads (SMEM path).
    const int4 st4 = *reinterpret_cast<const int4*>(slot_type  + b * S);
    const int4 cl4 = *reinterpret_cast<const int4*>(char_len   + b * S);
    const int4 ai4 = *reinterpret_cast<const int4*>(action_ids + b * S);

    const vfloat4 bos =
        *(reinterpret_cast<const vfloat4*>(action_table + BOS_ID * D) + lane);

    vfloat4* outv = reinterpret_cast<vfloat4*>(out + (size_t)b * 5 * D) + lane;
    __builtin_nontemporal_store(bos, &outv[0]);    // BOS row

    #pragma unroll
    for (int s = 0; s < S; ++s) {
        const int t   = __builtin_amdgcn_readfirstlane(
            (s == 0) ? st4.x : (s == 1) ? st4.y : (s == 2) ? st4.z : st4.w);
        const int len = __builtin_amdgcn_readfirstlane(
            (s == 0) ? cl4.x : (s == 1) ? cl4.y : (s == 2) ? cl4.z : cl4.w);
        const int aid = __builtin_amdgcn_readfirstlane(
            (s == 0) ? ai4.x : (s == 1) ? ai4.y : (s == 2) ? ai4.z : ai4.w);

        vfloat4 r = {0.f, 0.f, 0.f, 0.f};

        if (t == 1) {
            r = *(reinterpret_cast<const vfloat4*>(action_table + aid * D) + lane);
        } else if (t == 0) {
            // 16 wave-uniform char ids for this slot -> SGPRs (one s_load_x16).
            const int* __restrict__ idp = char_ids + b * (S * L) + s * L;
            int id[L];
            #pragma unroll
            for (int l = 0; l < L; ++l)
                id[l] = __builtin_amdgcn_readfirstlane(idp[l]);

            // Groups of 4 gathers; group guard is a wave-uniform scalar
            // branch, per-element {0,1} masks keep the sum bit-exact.
            #pragma unroll
            for (int g = 0; g < 4; ++g) {
                if (len > 4 * g) {
                    vfloat4 e0 = *(reinterpret_cast<const vfloat4*>(
                                       char_table + id[4 * g + 0] * D) + lane);
                    vfloat4 e1 = *(reinterpret_cast<const vfloat4*>(
                                       char_table + id[4 * g + 1] * D) + lane);
                    vfloat4 e2 = *(reinterpret_cast<const vfloat4*>(
                                       char_table + id[4 * g + 2] * D) + lane);
                    vfloat4 e3 = *(reinterpret_cast<const vfloat4*>(
                                       char_table + id[4 * g + 3] * D) + lane);
                    const float m0 = (4 * g + 0 < len) ? 1.0f : 0.0f;
                    const float m1 = (4 * g + 1 < len) ? 1.0f : 0.0f;
                    const float m2 = (4 * g + 2 < len) ? 1.0f : 0.0f;
                    const float m3 = (4 * g + 3 < len) ? 1.0f : 0.0f;
                    r += m0 * e0;
                    r += m1 * e1;
                    r += m2 * e2;
                    r += m3 * e3;
                }
            }
            const float flen = (float)len;
            r /= flen;                         // exact f32 div, matches ref
        }
        // t == 2: zeros

        __builtin_nontemporal_store(r, &outv[(s + 1) * (D / 4)]);
    }
}

extern "C" void kernel_launch(void* const* d_in, const int* in_sizes, int n_in,
                              void* d_out, int out_size, void* d_ws, size_t ws_size,
                              hipStream_t stream) {
    const int*   char_ids     = (const int*)  d_in[0];
    const int*   char_len     = (const int*)  d_in[1];
    const int*   action_ids   = (const int*)  d_in[2];
    const int*   slot_type    = (const int*)  d_in[3];
    const float* char_table   = (const float*)d_in[4];
    const float* action_table = (const float*)d_in[5];
    float*       out          = (float*)      d_out;

    // One wave per batch element: 16384 waves; 256-thread blocks -> 4096 blocks.
    const int blocks = B / 4;
    actions_emb_wave5<<<blocks, 256, 0, stream>>>(
        char_ids, char_len, action_ids, slot_type, char_table, action_table, out);
}

// Round 3
// 106.627 us; speedup vs baseline: 1.0886x; 1.0480x over previous
//
#include <hip/hip_runtime.h>

// Problem constants (from reference)
constexpr int B = 16384;
constexpr int S = 4;
constexpr int L = 16;
constexpr int D = 256;           // 256 floats per row = 64 lanes x float4
constexpr int BOS_ID = 98;

typedef float vfloat4 __attribute__((ext_vector_type(4)));

// v4: IDENTICAL to v3 except stores are PLAIN (L2 write-back), not
// __builtin_nontemporal_store. Rationale: three structurally different
// load/compute organizations (v1/v2/v3) all measured ~112-116 us, so the
// bottleneck is in what they share — the NT store path. The harness's own
// fillBufferAligned sustains 6.2 TB/s with plain stores; our NT-store
// kernel implies ~1.5 TB/s on the same chip. NT (no-allocate) stores
// bypass L2 write-combining on gfx950 and were never bandwidth-validated.
__global__ __launch_bounds__(256, 8) void actions_emb_wave5(
    const int*   __restrict__ char_ids,     // (B,S,L) = (B,64)
    const int*   __restrict__ char_len,     // (B,S)
    const int*   __restrict__ action_ids,   // (B,S)
    const int*   __restrict__ slot_type,    // (B,S)
    const float* __restrict__ char_table,   // (58,D)
    const float* __restrict__ action_table, // (99,D)
    float*       __restrict__ out)          // (B,S+1,D)
{
    const int lane = threadIdx.x & 63;
    // one wave per batch element; readfirstlane makes b provably uniform
    const int b = __builtin_amdgcn_readfirstlane(
        (int)((blockIdx.x * blockDim.x + threadIdx.x) >> 6));

    // Wave-uniform control loads (SMEM path).
    const int4 st4 = *reinterpret_cast<const int4*>(slot_type  + b * S);
    const int4 cl4 = *reinterpret_cast<const int4*>(char_len   + b * S);
    const int4 ai4 = *reinterpret_cast<const int4*>(action_ids + b * S);

    const vfloat4 bos =
        *(reinterpret_cast<const vfloat4*>(action_table + BOS_ID * D) + lane);

    vfloat4* outv = reinterpret_cast<vfloat4*>(out + (size_t)b * 5 * D) + lane;
    outv[0] = bos;                                  // BOS row (plain store)

    #pragma unroll
    for (int s = 0; s < S; ++s) {
        const int t   = __builtin_amdgcn_readfirstlane(
            (s == 0) ? st4.x : (s == 1) ? st4.y : (s == 2) ? st4.z : st4.w);
        const int len = __builtin_amdgcn_readfirstlane(
            (s == 0) ? cl4.x : (s == 1) ? cl4.y : (s == 2) ? cl4.z : cl4.w);
        const int aid = __builtin_amdgcn_readfirstlane(
            (s == 0) ? ai4.x : (s == 1) ? ai4.y : (s == 2) ? ai4.z : ai4.w);

        vfloat4 r = {0.f, 0.f, 0.f, 0.f};

        if (t == 1) {
            r = *(reinterpret_cast<const vfloat4*>(action_table + aid * D) + lane);
        } else if (t == 0) {
            // 16 wave-uniform char ids for this slot -> SGPRs.
            const int* __restrict__ idp = char_ids + b * (S * L) + s * L;
            int id[L];
            #pragma unroll
            for (int l = 0; l < L; ++l)
                id[l] = __builtin_amdgcn_readfirstlane(idp[l]);

            // Groups of 4 gathers; group guard is a wave-uniform scalar
            // branch, per-element {0,1} masks keep the sum bit-exact
            // (fma(1,e,r)==r+e, fma(0,e,r)==r in f32, ascending l order).
            #pragma unroll
            for (int g = 0; g < 4; ++g) {
                if (len > 4 * g) {
                    vfloat4 e0 = *(reinterpret_cast<const vfloat4*>(
                                       char_table + id[4 * g + 0] * D) + lane);
                    vfloat4 e1 = *(reinterpret_cast<const vfloat4*>(
                                       char_table + id[4 * g + 1] * D) + lane);
                    vfloat4 e2 = *(reinterpret_cast<const vfloat4*>(
                                       char_table + id[4 * g + 2] * D) + lane);
                    vfloat4 e3 = *(reinterpret_cast<const vfloat4*>(
                                       char_table + id[4 * g + 3] * D) + lane);
                    const float m0 = (4 * g + 0 < len) ? 1.0f : 0.0f;
                    const float m1 = (4 * g + 1 < len) ? 1.0f : 0.0f;
                    const float m2 = (4 * g + 2 < len) ? 1.0f : 0.0f;
                    const float m3 = (4 * g + 3 < len) ? 1.0f : 0.0f;
                    r += m0 * e0;
                    r += m1 * e1;
                    r += m2 * e2;
                    r += m3 * e3;
                }
            }
            const float flen = (float)len;
            r /= flen;                         // exact f32 div, matches ref
        }
        // t == 2: zeros

        outv[(s + 1) * (D / 4)] = r;           // plain store
    }
}

extern "C" void kernel_launch(void* const* d_in, const int* in_sizes, int n_in,
                              void* d_out, int out_size, void* d_ws, size_t ws_size,
                              hipStream_t stream) {
    const int*   char_ids     = (const int*)  d_in[0];
    const int*   char_len     = (const int*)  d_in[1];
    const int*   action_ids   = (const int*)  d_in[2];
    const int*   slot_type    = (const int*)  d_in[3];
    const float* char_table   = (const float*)d_in[4];
    const float* action_table = (const float*)d_in[5];
    float*       out          = (float*)      d_out;

    // One wave per batch element: 16384 waves; 256-thread blocks -> 4096 blocks.
    const int blocks = B / 4;
    actions_emb_wave5<<<blocks, 256, 0, stream>>>(
        char_ids, char_len, action_ids, slot_type, char_table, action_table, out);
}